// Round 4
// baseline (30.086 us; speedup 1.0000x reference)
//
#include <hip/hip_runtime.h>
#include <hip/hip_bf16.h>
#include <math.h>

// Problem: B=8, H=W=256, C=10 metric channels, all fp32.
// ws float layout: [0..255] = per-block partial maxes of mass;
//                  [1024 .. 1024+8*257*10) = per-batch LUT of T(mass), stride 10.
#define GH 256
#define GW 256
#define NC 10
#define NKNOT 257

__device__ __forceinline__ float gelu_exact(float x) {
    return 0.5f * x * (1.0f + erff(x * 0.70710678118654752f));
}
__device__ __forceinline__ float softplus_f(float x) {
    if (x > 20.f) return x;
    return log1pf(expf(x));
}

// ---- Kernel 1: blocks 0..513 build LUT (one wave per (batch,knot));
//      blocks 514..769 compute partial max of mass (float4 loads).
__global__ __launch_bounds__(256) void k_pre(
        const float* __restrict__ mass,
        const float* __restrict__ vel,
        const float* __restrict__ e_w1, const float* __restrict__ e_b1,
        const float* __restrict__ e_w2, const float* __restrict__ e_b2,
        const float* __restrict__ m_w1, const float* __restrict__ m_b1,
        const float* __restrict__ m_w2, const float* __restrict__ m_b2,
        const float* __restrict__ s_w1, const float* __restrict__ s_b1,
        const float* __restrict__ s_w2, const float* __restrict__ s_b2,
        float* __restrict__ ws) {
    const int tid = threadIdx.x;
    if (blockIdx.x >= 514) {  // ---- partial max over mass
        const int pb = blockIdx.x - 514;           // 0..255
        const float4* mass4 = (const float4*)mass; // 131072 float4 total
        int base = pb * 512 + tid;                 // 512 float4 per block
        float4 a = mass4[base];
        float4 c = mass4[base + 256];
        float v = fmaxf(fmaxf(fmaxf(a.x, a.y), fmaxf(a.z, a.w)),
                        fmaxf(fmaxf(c.x, c.y), fmaxf(c.z, c.w)));
        #pragma unroll
        for (int off = 32; off > 0; off >>= 1)
            v = fmaxf(v, __shfl_xor(v, off, 64));
        __shared__ float sred[4];
        if ((tid & 63) == 0) sred[tid >> 6] = v;
        __syncthreads();
        if (tid == 0)
            ws[pb] = fmaxf(fmaxf(sred[0], sred[1]), fmaxf(sred[2], sred[3]));
        return;
    }
    // ---- LUT build: wave-parallel over hidden dim
    const int wave = blockIdx.x * 4 + (tid >> 6);   // 0..2055 == 8*257-1
    const int lane = tid & 63;
    const int b = wave / NKNOT, knot = wave % NKNOT;
    const float m = (float)knot * (1.0f / 256.0f);
    const float vx = vel[b * 3 + 0], vy = vel[b * 3 + 1], vz = vel[b * 3 + 2];

    float acc[10];
    {   // energy hidden unit `lane`
        float pre = m * e_w1[lane] + vx * e_w1[64 + lane] + vy * e_w1[128 + lane]
                  + vz * e_w1[192 + lane] + e_b1[lane];
        acc[0] = gelu_exact(pre) * e_w2[lane];
    }
    {   // momentum hidden unit `lane`
        float pre = m * m_w1[lane] + vx * m_w1[64 + lane] + vy * m_w1[128 + lane]
                  + vz * m_w1[192 + lane] + m_b1[lane];
        float h = gelu_exact(pre);
        acc[1] = h * m_w2[lane * 3 + 0];
        acc[2] = h * m_w2[lane * 3 + 1];
        acc[3] = h * m_w2[lane * 3 + 2];
    }
    {   // stress hidden units `lane`, `lane+64`
        float pre0 = m * s_w1[lane] + vx * s_w1[128 + lane] + vy * s_w1[256 + lane]
                   + vz * s_w1[384 + lane] + s_b1[lane];
        float pre1 = m * s_w1[64 + lane] + vx * s_w1[192 + lane] + vy * s_w1[320 + lane]
                   + vz * s_w1[448 + lane] + s_b1[64 + lane];
        float h0 = gelu_exact(pre0), h1 = gelu_exact(pre1);
        #pragma unroll
        for (int k = 0; k < 6; k++)
            acc[4 + k] = h0 * s_w2[lane * 6 + k] + h1 * s_w2[(lane + 64) * 6 + k];
    }
    #pragma unroll
    for (int c = 0; c < 10; c++) {
        float v = acc[c];
        #pragma unroll
        for (int off = 32; off > 0; off >>= 1)
            v += __shfl_xor(v, off, 64);
        acc[c] = v;
    }
    if (lane == 0) {
        float* lut = ws + 1024 + (size_t)(b * NKNOT + knot) * NC;
        lut[0] = softplus_f(acc[0] + e_b2[0]);
        lut[1] = acc[1] + m_b2[0];
        lut[2] = acc[2] + m_b2[1];
        lut[3] = acc[3] + m_b2[2];
        #pragma unroll
        for (int k = 0; k < 6; k++) lut[4 + k] = acc[4 + k] + s_b2[k];
    }
}

// ---- Kernel 2: 32x32 tile, 2x2 register patch per thread.
// Region (pre-smooth metric) = 34x34, mass halo tile = 40x44.
__global__ __launch_bounds__(256, 2) void k_main(const float* __restrict__ mass,
                                                 const float* __restrict__ minit,
                                                 const float* __restrict__ solver,
                                                 const float* __restrict__ ws,
                                                 float* __restrict__ out) {
    const int b = blockIdx.z;
    const int tid = threadIdx.x;
    const int tile_x = blockIdx.x * 32, tile_y = blockIdx.y * 32;

    __shared__ float  s_mass[40][44];        // global (tile-4+my, tile-4+mx)
    __shared__ float2 s_met2[5][34][34];     // region r -> global tile + r - 1
    __shared__ float2 s_lut2[NKNOT * 6];     // 48B-stride LUT (slot 5 unused)
    __shared__ float  s_wmax[4];

    // finalize global max (256 partials, 1/thread)
    {
        float v = ws[tid];
        #pragma unroll
        for (int off = 32; off > 0; off >>= 1)
            v = fmaxf(v, __shfl_xor(v, off, 64));
        if ((tid & 63) == 0) s_wmax[tid >> 6] = v;
    }
    // LUT load with stride remap 5 -> 6 (for 16B-aligned lerp reads)
    {
        const float2* lutg2 = (const float2*)(ws + 1024 + (size_t)b * NKNOT * NC);
        for (int i = tid; i < NKNOT * 5; i += 256) {
            int k = i / 5, c = i % 5;
            s_lut2[k * 6 + c] = lutg2[i];
        }
    }
    // mass tile load as float2 (40 rows x 22 float2); zero outside image
    {
        const float* massb = mass + (size_t)b * GH * GW;
        for (int i = tid; i < 40 * 22; i += 256) {
            int my = i / 22, jx = i % 22;
            int gy = tile_y - 4 + my, gx = tile_x - 4 + 2 * jx;
            float2 v = make_float2(0.f, 0.f);
            if ((unsigned)gy < GH && (unsigned)gx < GW)  // gx even: pair all-in or all-out
                v = *(const float2*)(massb + gy * GW + gx);
            *(float2*)&s_mass[my][2 * jx] = v;
        }
    }
    // softmax(solver_params)
    float p0 = solver[0], p1 = solver[1], p2 = solver[2];
    float pm = fmaxf(p0, fmaxf(p1, p2));
    float e0 = expf(p0 - pm), e1 = expf(p1 - pm), e2 = expf(p2 - pm);
    float inv = 1.f / (e0 + e1 + e2);
    float w0 = e0 * inv, w1 = e1 * inv, w2 = e2 * inv;

    __syncthreads();

    const float gmax = fmaxf(fmaxf(s_wmax[0], s_wmax[1]), fmaxf(s_wmax[2], s_wmax[3]));
    const float k0 = -25.132741228718345f * w0;          // w0 * (-8*pi*G/c^4)
    const float potscale = 2.f * w1 / (gmax + 1e-8f);    // folds mass normalization

    // Green weights: GWt[|dy|][|dx|] = -1/(2*pi*sqrt(dy^2+dx^2)), center 0
    constexpr float GWt[4][4] = {
        {0.f,            -0.15915494f, -0.07957747f, -0.05305165f},
        {-0.15915494f,   -0.11253954f, -0.07117625f, -0.05033165f},
        {-0.07957747f,   -0.07117625f, -0.05626977f, -0.04414183f},
        {-0.05305165f,   -0.05033165f, -0.04414183f, -0.03751318f}};

    // ---- stage 2: 17x17 patches of 2x2 region pixels
    for (int item = tid; item < 17 * 17; item += 256) {
        const int py = item / 17, px = item % 17;
        const int ry0 = 2 * py, rx0 = 2 * px;
        float potTL = 0.f, potTR = 0.f, potBL = 0.f, potBR = 0.f;
        #pragma unroll
        for (int k = 0; k < 8; k++) {
            const float2* mr = (const float2*)&s_mass[ry0 + k][rx0];
            float v[10];
            #pragma unroll
            for (int h = 0; h < 5; h++) {
                float2 t = mr[h];
                v[2 * h] = t.x; v[2 * h + 1] = t.y;
            }
            #pragma unroll
            for (int j = 0; j < 10; j++) {
                const int dyt = k - 3, dyb = k - 4;
                const int dxl = j - 3, dxr = j - 4;
                const int at = dyt < 0 ? -dyt : dyt, ab = dyb < 0 ? -dyb : dyb;
                const int al = dxl < 0 ? -dxl : dxl, ar = dxr < 0 ? -dxr : dxr;
                if (k <= 6 && j <= 6 && !(k == 3 && j == 3)) potTL += GWt[at][al] * v[j];
                if (k <= 6 && j >= 1 && j <= 7 && !(k == 3 && j == 4)) potTR += GWt[at][ar] * v[j];
                if (k >= 1 && j <= 6 && !(k == 4 && j == 3)) potBL += GWt[ab][al] * v[j];
                if (k >= 1 && j >= 1 && j <= 7 && !(k == 4 && j == 4)) potBR += GWt[ab][ar] * v[j];
            }
        }
        const float pots[4] = {potTL, potTR, potBL, potBR};
        #pragma unroll
        for (int p = 0; p < 4; p++) {
            const int ry = ry0 + (p >> 1), rx = rx0 + (p & 1);
            const int gy = tile_y + ry - 1, gx = tile_x + rx - 1;
            if ((unsigned)gy >= GH || (unsigned)gx >= GW) {
                #pragma unroll
                for (int cp = 0; cp < 5; cp++)
                    s_met2[cp][ry][rx] = make_float2(0.f, 0.f);
                continue;
            }
            const float m = s_mass[ry + 3][rx + 3];
            const float potterm = potscale * pots[p];
            float x = m * 256.f;
            int i0 = (int)x;
            i0 = i0 < 255 ? i0 : 255;
            const float f = x - (float)i0;
            const float4* L0 = (const float4*)&s_lut2[i0 * 6];
            const float4* L1 = (const float4*)&s_lut2[(i0 + 1) * 6];
            float4 a01 = L0[0], a23 = L0[1];
            float4 b01 = L1[0], b23 = L1[1];
            float2 a4 = s_lut2[i0 * 6 + 4], b4 = s_lut2[(i0 + 1) * 6 + 4];
            const float2* mi2 = (const float2*)(minit + ((size_t)(b * GH + gy) * GW + gx) * NC);
            float2 mi0 = mi2[0], mi1 = mi2[1], mi2v = mi2[2], mi3 = mi2[3], mi4 = mi2[4];
            float2 r;
            // cp0: c0,c1
            r.x = fmaf(k0, fmaf(f, b01.x - a01.x, a01.x), mi0.x);
            r.y = fmaf(k0, fmaf(f, b01.y - a01.y, a01.y), mi0.y);
            r.x = fminf(r.x, -0.1f);
            s_met2[0][ry][rx] = r;
            // cp1: c2,c3
            r.x = fmaf(k0, fmaf(f, b01.z - a01.z, a01.z), mi1.x);
            r.y = fmaf(k0, fmaf(f, b01.w - a01.w, a01.w), mi1.y);
            s_met2[1][ry][rx] = r;
            // cp2: c4,c5
            r.x = fmaf(k0, fmaf(f, b23.x - a23.x, a23.x), mi2v.x) + potterm;
            r.y = fmaf(k0, fmaf(f, b23.y - a23.y, a23.y), mi2v.y);
            r.x = fmaxf(r.x, 0.1f);
            s_met2[2][ry][rx] = r;
            // cp3: c6,c7
            r.x = fmaf(k0, fmaf(f, b23.z - a23.z, a23.z), mi3.x);
            r.y = fmaf(k0, fmaf(f, b23.w - a23.w, a23.w), mi3.y) + potterm;
            r.y = fmaxf(r.y, 0.1f);
            s_met2[3][ry][rx] = r;
            // cp4: c8,c9
            r.x = fmaf(k0, fmaf(f, b4.x - a4.x, a4.x), mi4.x);
            r.y = fmaf(k0, fmaf(f, b4.y - a4.y, a4.y), mi4.y);
            r.y = fmaxf(r.y, 0.1f);
            s_met2[4][ry][rx] = r;
        }
    }
    __syncthreads();

    // ---- stage 3: per-thread 2x2 output patch; separable 3x3 in registers
    const int py = tid >> 4, px = tid & 15;
    const int oy0 = 2 * py, ox0 = 2 * px;
    const float g0 = 0.274068619f, g1 = 0.451862761f;
    const bool do_smooth = (w2 > 0.1f);
    float2 res[4][5];
    #pragma unroll
    for (int cp = 0; cp < 5; cp++) {
        float2 c0[4], c1[4], c2[4], c3[4];
        #pragma unroll
        for (int rr = 0; rr < 4; rr++) {
            const float4* row = (const float4*)&s_met2[cp][oy0 + rr][ox0];
            float4 a = row[0], bq = row[1];
            c0[rr] = make_float2(a.x, a.y);
            c1[rr] = make_float2(a.z, a.w);
            c2[rr] = make_float2(bq.x, bq.y);
            c3[rr] = make_float2(bq.z, bq.w);
        }
        if (do_smooth) {
            float2 HL[4], HR[4];
            #pragma unroll
            for (int rr = 0; rr < 4; rr++) {
                HL[rr].x = fmaf(g0, c0[rr].x + c2[rr].x, g1 * c1[rr].x);
                HL[rr].y = fmaf(g0, c0[rr].y + c2[rr].y, g1 * c1[rr].y);
                HR[rr].x = fmaf(g0, c1[rr].x + c3[rr].x, g1 * c2[rr].x);
                HR[rr].y = fmaf(g0, c1[rr].y + c3[rr].y, g1 * c2[rr].y);
            }
            res[0][cp].x = fmaf(g0, HL[0].x + HL[2].x, g1 * HL[1].x);
            res[0][cp].y = fmaf(g0, HL[0].y + HL[2].y, g1 * HL[1].y);
            res[1][cp].x = fmaf(g0, HR[0].x + HR[2].x, g1 * HR[1].x);
            res[1][cp].y = fmaf(g0, HR[0].y + HR[2].y, g1 * HR[1].y);
            res[2][cp].x = fmaf(g0, HL[1].x + HL[3].x, g1 * HL[2].x);
            res[2][cp].y = fmaf(g0, HL[1].y + HL[3].y, g1 * HL[2].y);
            res[3][cp].x = fmaf(g0, HR[1].x + HR[3].x, g1 * HR[2].x);
            res[3][cp].y = fmaf(g0, HR[1].y + HR[3].y, g1 * HR[2].y);
        } else {
            res[0][cp] = c1[1];
            res[1][cp] = c2[1];
            res[2][cp] = c1[2];
            res[3][cp] = c2[2];
        }
    }
    #pragma unroll
    for (int p = 0; p < 4; p++) {
        const int oy = oy0 + (p >> 1), ox = ox0 + (p & 1);
        float2* dst = (float2*)(out + ((size_t)(b * GH + tile_y + oy) * GW + tile_x + ox) * NC);
        #pragma unroll
        for (int cp = 0; cp < 5; cp++) dst[cp] = res[p][cp];
    }
}

extern "C" void kernel_launch(void* const* d_in, const int* in_sizes, int n_in,
                              void* d_out, int out_size, void* d_ws, size_t ws_size,
                              hipStream_t stream) {
    const float* mass   = (const float*)d_in[0];
    const float* vel    = (const float*)d_in[1];
    const float* minit  = (const float*)d_in[2];
    const float* e_w1   = (const float*)d_in[3];
    const float* e_b1   = (const float*)d_in[4];
    const float* e_w2   = (const float*)d_in[5];
    const float* e_b2   = (const float*)d_in[6];
    const float* m_w1   = (const float*)d_in[7];
    const float* m_b1   = (const float*)d_in[8];
    const float* m_w2   = (const float*)d_in[9];
    const float* m_b2   = (const float*)d_in[10];
    const float* s_w1   = (const float*)d_in[11];
    const float* s_b1   = (const float*)d_in[12];
    const float* s_w2   = (const float*)d_in[13];
    const float* s_b2   = (const float*)d_in[14];
    const float* solver = (const float*)d_in[15];
    float* ws  = (float*)d_ws;
    float* out = (float*)d_out;

    k_pre<<<770, 256, 0, stream>>>(mass, vel, e_w1, e_b1, e_w2, e_b2,
                                   m_w1, m_b1, m_w2, m_b2,
                                   s_w1, s_b1, s_w2, s_b2, ws);
    dim3 grid(8, 8, 8);
    k_main<<<grid, 256, 0, stream>>>(mass, minit, solver, ws, out);
}